// Round 4
// baseline (540.811 us; speedup 1.0000x reference)
//
#include <hip/hip_runtime.h>

typedef __bf16 bf16;
typedef __bf16 bf16x4 __attribute__((ext_vector_type(4)));
typedef __bf16 bf16x8 __attribute__((ext_vector_type(8)));
typedef float  fx4    __attribute__((ext_vector_type(4)));

#define MFMA16(a, b, c) __builtin_amdgcn_mfma_f32_16x16x32_bf16((a), (b), (c), 0, 0, 0)

// Problem constants: B=4, N=2048, E=768, H=8, D=96; M = B*N = 8192

// ---------------------------------------------------------------------------
// Device-side dtype probe (block-uniform). Interprets the first 1024
// halfwords of p as bf16. True-bf16 data here has max|.| < 16; if the buffer
// holds fp32, ~42% of the (uniform-random) low-mantissa halfwords decode to
// |bf16| > 1e6 or NaN -> triggers with certainty over 1024 samples.
// ---------------------------------------------------------------------------
__device__ __forceinline__ int probe_is_fp32(const void* w, int lane) {
  const unsigned short* p = (const unsigned short*)w;
  int bad = 0;
#pragma unroll
  for (int i = 0; i < 16; i++) {
    float v = __uint_as_float(((unsigned)p[lane * 16 + i]) << 16);
    if (!(__builtin_fabsf(v) <= 1e6f)) bad = 1;  // catches NaN too
  }
  return __any(bad);
}

// ---------------------------------------------------------------------------
// GEMM: C[M,768] = A[M,768] @ W[768,768]^T + bias   (torch Linear layout)
// Tile 128x128, BK=32, 256 threads = 4 waves in 2x2, each wave 64x64 via
// 4x4 of 16x16x32 MFMAs. A and W dtypes probed INDEPENDENTLY (the final
// projection mixes bf16 A (our intermediate) with fp32 W (user weight) —
// round-3 bug was sharing one flag).
// TRANSV=1 writes V transposed as Vt[b*768+o][n] (always bf16).
// OUT32=1: store fp32 when W is fp32 (output dtype follows user dtype).
// ---------------------------------------------------------------------------
template<int TRANSV, int OUT32>
__global__ __launch_bounds__(256)
void gemm_bt(const void* __restrict__ Av, const void* __restrict__ Wv_,
             const void* __restrict__ biasv, void* __restrict__ Cv) {
  constexpr int K = 768;
  __shared__ __align__(16) bf16 As[128 * 32];
  __shared__ __align__(16) bf16 Bs[128 * 32];

  const int tid  = threadIdx.x;
  const int wave = tid >> 6;
  const int lane = tid & 63;
  const int l15  = lane & 15;
  const int q4   = lane >> 4;
  const int wr   = wave >> 1;
  const int wc   = wave & 1;
  const int rb0  = blockIdx.y * 128;
  const int cb0  = blockIdx.x * 128;

  const int a32 = probe_is_fp32(Av, lane);
  const int w32 = probe_is_fp32(Wv_, lane);

  const bf16*  Ab = (const bf16*)Av;
  const bf16*  Wb = (const bf16*)Wv_;
  const float* Af = (const float*)Av;
  const float* Wf = (const float*)Wv_;

  fx4 acc[4][4];
#pragma unroll
  for (int i = 0; i < 4; i++)
#pragma unroll
    for (int j = 0; j < 4; j++) acc[i][j] = (fx4){0.f, 0.f, 0.f, 0.f};

  for (int k0 = 0; k0 < K; k0 += 32) {
    // Stage A,B tiles: each tile is 128x32 bf16; 512 chunks of 8 elements.
    for (int c = tid; c < 512; c += 256) {
      const int row = c >> 2;
      const int kc  = (c & 3) << 3;
      if (a32) {
        const float* sa = Af + (size_t)(rb0 + row) * K + k0 + kc;
        bf16x8 pa;
#pragma unroll
        for (int t = 0; t < 8; t++) pa[t] = (bf16)sa[t];
        *(bf16x8*)&As[row * 32 + kc] = pa;
      } else {
        *(uint4*)&As[row * 32 + kc] =
            *(const uint4*)&Ab[(size_t)(rb0 + row) * K + k0 + kc];
      }
      if (w32) {
        const float* sb = Wf + (size_t)(cb0 + row) * K + k0 + kc;
        bf16x8 pb;
#pragma unroll
        for (int t = 0; t < 8; t++) pb[t] = (bf16)sb[t];
        *(bf16x8*)&Bs[row * 32 + kc] = pb;
      } else {
        *(uint4*)&Bs[row * 32 + kc] =
            *(const uint4*)&Wb[(size_t)(cb0 + row) * K + k0 + kc];
      }
    }
    __syncthreads();

    bf16x8 a[4], b[4];
#pragma unroll
    for (int i = 0; i < 4; i++)
      a[i] = *(const bf16x8*)&As[(wr * 64 + i * 16 + l15) * 32 + q4 * 8];
#pragma unroll
    for (int j = 0; j < 4; j++)
      b[j] = *(const bf16x8*)&Bs[(wc * 64 + j * 16 + l15) * 32 + q4 * 8];
#pragma unroll
    for (int i = 0; i < 4; i++)
#pragma unroll
      for (int j = 0; j < 4; j++)
        acc[i][j] = MFMA16(a[i], b[j], acc[i][j]);
    __syncthreads();
  }

  // Epilogue. C/D layout: col = lane&15, row = (lane>>4)*4 + reg.
  const int cb = cb0 + wc * 64;
  const int rb = rb0 + wr * 64;
#pragma unroll
  for (int j = 0; j < 4; j++) {
    const int o  = cb + j * 16 + l15;
    const float bj = w32 ? ((const float*)biasv)[o]
                         : (float)((const bf16*)biasv)[o];
#pragma unroll
    for (int i = 0; i < 4; i++) {
      const int r0 = rb + i * 16 + q4 * 4;
      if (TRANSV) {
        // write Vt[(batch*768 + o)*2048 + n], n = row within batch (bf16)
        const int bb = r0 >> 11;
        const int n0 = r0 & 2047;
        bf16x4 pk;
#pragma unroll
        for (int r = 0; r < 4; r++) pk[r] = (bf16)(acc[i][j][r] + bj);
        *(bf16x4*)&((bf16*)Cv)[((size_t)(bb * 768 + o)) * 2048 + n0] = pk;
      } else if (OUT32) {
        if (w32) {
#pragma unroll
          for (int r = 0; r < 4; r++)
            ((float*)Cv)[(size_t)(r0 + r) * 768 + o] = acc[i][j][r] + bj;
        } else {
#pragma unroll
          for (int r = 0; r < 4; r++)
            ((bf16*)Cv)[(size_t)(r0 + r) * 768 + o] = (bf16)(acc[i][j][r] + bj);
        }
      } else {
#pragma unroll
        for (int r = 0; r < 4; r++)
          ((bf16*)Cv)[(size_t)(r0 + r) * 768 + o] = (bf16)(acc[i][j][r] + bj);
      }
    }
  }
}

// ---------------------------------------------------------------------------
// Attention with softmax over HEADS (dim=1), then / sqrt(768).
// Block = 512 threads = 8 waves; wave w owns head w. TQ=TK=32.
// Grid = 4 batches * 64 q-tiles = 256 blocks. All inputs here are our own
// bf16 intermediates. AO aliases Q (block reads only its own 32 rows before
// the loop, writes only those rows after it).
// ---------------------------------------------------------------------------
__global__ __launch_bounds__(512)
void attn_kernel(const bf16* Q, const bf16* __restrict__ Kb,
                 const bf16* __restrict__ Vt, bf16* AO) {
  __shared__ __align__(16) float Ebuf[32 * 8 * 32];  // [q][h][k]  32 KB
  __shared__ __align__(16) bf16  Pbuf[8 * 32 * 32];  // [h][q][k]  16 KB

  const int tid  = threadIdx.x;
  const int h    = tid >> 6;
  const int lane = tid & 63;
  const int l15  = lane & 15;
  const int q4   = lane >> 4;
  const int b    = blockIdx.x >> 6;
  const int qt   = blockIdx.x & 63;
  const int qrow0 = b * 2048 + qt * 32;

  // Persistent Q fragments: A[m=lane&15][k=quad*8+j] over 2 q-16tiles, 3 d-chunks
  bf16x8 aq[2][3];
#pragma unroll
  for (int i = 0; i < 2; i++)
#pragma unroll
    for (int c = 0; c < 3; c++)
      aq[i][c] = *(const bf16x8*)
          &Q[(size_t)(qrow0 + i * 16 + l15) * 768 + h * 96 + c * 32 + q4 * 8];

  fx4 o[2][6];
#pragma unroll
  for (int i = 0; i < 2; i++)
#pragma unroll
    for (int j = 0; j < 6; j++) o[i][j] = (fx4){0.f, 0.f, 0.f, 0.f};

  for (int kt = 0; kt < 64; kt++) {
    const int krow0 = b * 2048 + kt * 32;

    // E = Q K^T for this head: [32q x 32k]
    fx4 e[2][2];
    e[0][0] = e[0][1] = e[1][0] = e[1][1] = (fx4){0.f, 0.f, 0.f, 0.f};
#pragma unroll
    for (int c = 0; c < 3; c++) {
#pragma unroll
      for (int j = 0; j < 2; j++) {
        bf16x8 bk = *(const bf16x8*)
            &Kb[(size_t)(krow0 + j * 16 + l15) * 768 + h * 96 + c * 32 + q4 * 8];
        e[0][j] = MFMA16(aq[0][c], bk, e[0][j]);
        e[1][j] = MFMA16(aq[1][c], bk, e[1][j]);
      }
    }
    // Scatter E into LDS [q][h][k]
#pragma unroll
    for (int i = 0; i < 2; i++)
#pragma unroll
      for (int j = 0; j < 2; j++)
#pragma unroll
        for (int r = 0; r < 4; r++)
          Ebuf[((i * 16 + q4 * 4 + r) * 8 + h) * 32 + (j * 16 + l15)] =
              e[i][j][r];
    __syncthreads();

    // Softmax across the 8 heads, / sqrt(768). 1024 (q,k) pairs, 512 threads.
    for (int p = tid; p < 1024; p += 512) {
      const int q = p >> 5, k = p & 31;
      float v[8];
#pragma unroll
      for (int hh = 0; hh < 8; hh++) v[hh] = Ebuf[(q * 8 + hh) * 32 + k];
      float m = v[0];
#pragma unroll
      for (int hh = 1; hh < 8; hh++) m = fmaxf(m, v[hh]);
      float s = 0.f;
#pragma unroll
      for (int hh = 0; hh < 8; hh++) { v[hh] = __expf(v[hh] - m); s += v[hh]; }
      const float inv = 1.0f / (s * 27.712812921102035f);  // / sqrt(768)
#pragma unroll
      for (int hh = 0; hh < 8; hh++)
        Pbuf[hh * 1024 + p] = (bf16)(v[hh] * inv);
    }
    __syncthreads();

    // O += P @ V  (A = P from LDS, B = V columns from Vt rows)
    bf16x8 ap[2];
#pragma unroll
    for (int i = 0; i < 2; i++)
      ap[i] = *(const bf16x8*)&Pbuf[h * 1024 + (i * 16 + l15) * 32 + q4 * 8];
#pragma unroll
    for (int j2 = 0; j2 < 6; j2++) {
      bf16x8 bv = *(const bf16x8*)
          &Vt[(size_t)((b * 8 + h) * 96 + j2 * 16 + l15) * 2048 + kt * 32 + q4 * 8];
      o[0][j2] = MFMA16(ap[0], bv, o[0][j2]);
      o[1][j2] = MFMA16(ap[1], bv, o[1][j2]);
    }
    // No third barrier needed: Ebuf rewrites are gated by this iter's
    // barrier 2 (all softmax reads complete before each thread's barrier-2
    // arrival); Pbuf rewrites happen after the NEXT barrier 1, by which time
    // this iter's ap reads have drained (barrier implies waitcnt).
  }

  // Write AO[row = qrow0+q][col = h*96 + d]
#pragma unroll
  for (int i = 0; i < 2; i++)
#pragma unroll
    for (int j2 = 0; j2 < 6; j2++)
#pragma unroll
      for (int r = 0; r < 4; r++)
        AO[(size_t)(qrow0 + i * 16 + q4 * 4 + r) * 768 + h * 96 + j2 * 16 + l15] =
            (bf16)(o[i][j2][r]);
}

// ---------------------------------------------------------------------------
// ws: Q (12.58 MB) + Vt (12.58 MB) = 25.2 MB. K staged in d_out (>= 12.58 MB
// whether out is bf16 or fp32). AO aliases Q. Final projection overwrites
// d_out in the dtype matching the user weights (runtime probe).
// ---------------------------------------------------------------------------
extern "C" void kernel_launch(void* const* d_in, const int* in_sizes, int n_in,
                              void* d_out, int out_size, void* d_ws,
                              size_t ws_size, hipStream_t stream) {
  const void* x  = d_in[0];
  const void* Wq = d_in[1];
  const void* bq = d_in[2];
  const void* Wk = d_in[3];
  const void* bk = d_in[4];
  const void* Wv = d_in[5];
  const void* bv = d_in[6];
  const void* Wo = d_in[7];
  const void* bo = d_in[8];

  const size_t MN = (size_t)8192 * 768;
  bf16* Q  = (bf16*)d_ws;        // later reused as AO
  bf16* Vt = Q + MN;             // [ (b*8+h)*96 + d ][ 2048 ]
  bf16* Kw = (bf16*)d_out;       // K staged in d_out, dead after attn
  bf16* AO = Q;                  // aliases Q (see attn_kernel note)

  dim3 ggrid(6, 64);  // (N/128, M/128)
  gemm_bt<0, 0><<<ggrid, 256, 0, stream>>>(x, Wq, bq, Q);
  gemm_bt<0, 0><<<ggrid, 256, 0, stream>>>(x, Wk, bk, Kw);
  gemm_bt<1, 0><<<ggrid, 256, 0, stream>>>(x, Wv, bv, Vt);
  attn_kernel<<<256, 512, 0, stream>>>(Q, Kw, Vt, AO);
  gemm_bt<0, 1><<<ggrid, 256, 0, stream>>>(AO, Wo, bo, d_out);
}